// Round 1
// baseline (475.209 us; speedup 1.0000x reference)
//
#include <hip/hip_runtime.h>
#include <math.h>

// Problem constants (match reference)
constexpr int N  = 1024;
constexpr int D  = 128;
constexpr int S  = 200;
constexpr int D2 = D / 2;          // float2 elements per row

// One thread owns one (n, d-pair) chain; iterates all 200 steps.
// 65536 threads = 256 blocks x 256 threads = 1 block/CU on MI355X.
__global__ __launch_bounds__(256, 4) void langevin_kernel(
    const float2* __restrict__ x0,
    const float2* __restrict__ y0,
    const float2* __restrict__ mean,
    const float2* __restrict__ var,
    const float*  __restrict__ gammas,
    const float2* __restrict__ noise,   // [S][N][D2]
    float2* __restrict__ x_tot,         // [N][S][D2]
    float2* __restrict__ y_tot,         // [N][S][D2]
    float2* __restrict__ outp,          // [N][S][D2]
    float*  __restrict__ steps)         // [N][S]
{
    __shared__ float sg[S];
    __shared__ float ss[S];
    for (int i = threadIdx.x; i < S; i += 256) {
        float g = gammas[i];
        sg[i] = g;
        ss[i] = sqrtf(2.0f * g);
    }
    __syncthreads();

    const int idx = blockIdx.x * 256 + threadIdx.x;  // 0 .. N*D2-1
    const int n   = idx >> 6;                        // idx / D2
    const int dp  = idx & 63;                        // idx % D2

    float2 x       = x0[idx];
    const float2 y = y0[idx];
    const float2 m = mean[dp];
    const float2 v = var[dp];
    const float ivx = 1.0f / v.x;
    const float ivy = 1.0f / v.y;

    const float2* zp = noise + idx;                  // + k*N*D2 per step
    float2* xq = x_tot + (size_t)n * (S * D2) + dp;  // + k*D2 per step
    float2* yq = y_tot + (size_t)n * (S * D2) + dp;
    float2* oq = outp  + (size_t)n * (S * D2) + dp;
    float*  sq = steps + (size_t)n * S;

    #pragma unroll 4
    for (int k = 0; k < S; ++k) {
        const float g = sg[k];
        const float s = ss[k];
        const float2 z = zp[(size_t)k * (N * D2)];

        const float gx = g * ivx;
        const float gy = g * ivy;

        // t_old = x + g*(-(x-m)/v) = x - (g/v)*(x-m)
        const float tox = fmaf(-gx, x.x - m.x, x.x);
        const float toy = fmaf(-gy, x.y - m.y, x.y);
        // x_new = t_old + sqrt(2g)*z
        x.x = fmaf(s, z.x, tox);
        x.y = fmaf(s, z.y, toy);
        // t_new = x_new - (g/v)*(x_new-m)
        const float tnx = fmaf(-gx, x.x - m.x, x.x);
        const float tny = fmaf(-gy, x.y - m.y, x.y);

        float2 o;
        o.x = tox - tnx;
        o.y = toy - tny;

        xq[(size_t)k * D2] = x;
        yq[(size_t)k * D2] = y;
        oq[(size_t)k * D2] = o;
        if (dp == 0) sq[k] = (float)k;   // one lane per wave
    }
}

extern "C" void kernel_launch(void* const* d_in, const int* in_sizes, int n_in,
                              void* d_out, int out_size, void* d_ws, size_t ws_size,
                              hipStream_t stream)
{
    const float* x0     = (const float*)d_in[0];
    const float* y0     = (const float*)d_in[1];
    const float* mean   = (const float*)d_in[2];
    const float* var    = (const float*)d_in[3];
    const float* gammas = (const float*)d_in[4];
    const float* noise  = (const float*)d_in[5];

    float* x_tot = (float*)d_out;                       // N*S*D
    float* y_tot = x_tot + (size_t)N * S * D;           // N*S*D
    float* outp  = y_tot + (size_t)N * S * D;           // N*S*D
    float* steps = outp  + (size_t)N * S * D;           // N*S

    dim3 grid((N * D2) / 256);   // 256 blocks
    dim3 block(256);
    langevin_kernel<<<grid, block, 0, stream>>>(
        (const float2*)x0, (const float2*)y0, (const float2*)mean,
        (const float2*)var, gammas, (const float2*)noise,
        (float2*)x_tot, (float2*)y_tot, (float2*)outp, steps);
}